// Round 5
// baseline (571.365 us; speedup 1.0000x reference)
//
#include <hip/hip_runtime.h>
#include <hip/hip_bf16.h>
#include <math.h>

#define NBATCH 2048
#define NAG 32
#define HIDD 256
#define INDIM 256
#define PIN 320
#define NACTN 20
#define NEGV -1e10f

typedef __attribute__((ext_vector_type(8))) __bf16 bf16x8;
typedef __attribute__((ext_vector_type(4))) float f32x4;

// LDS regions (byte offsets). All bf16 activation buffers are 32x256,
// XOR-swizzled (frag ^= row&7), stride 256 elems, no padding.
#define OFF_X   0         // bf16: input -> x -> p1x (overlaid live ranges)
#define OFF_QK  16384     // bf16 h_old (32x256) -> fp32 q|k (32x132)
#define OFF_H   33280     // bf16 h_new
#define OFF_V   49664     // bf16 v (32x68) -> bf16 msg (32x64 swizzled)
#define OFF_G   54016     // bf16 g (32x4)
#define SMEM_TOTAL 54272  // -> 3 blocks/CU (3*54272 = 162816 <= 163840)
#define QKSTR 132         // fp32 q|k row stride (q cols 0-63, k cols 64-127)

// bf16 weight cache layout in d_ws (element offsets)
#define WO_W1   0
#define WO_WIH  65536
#define WO_WHH  262144
#define WO_WQ   458752
#define WO_WK   475136
#define WO_WV   491520
#define WO_WG   507904
#define WO_WP1  508928
#define WO_WP2  590848

__device__ __forceinline__ unsigned short f2bf(float f) {
    union { float f; unsigned int i; } x; x.f = f;
    unsigned int r = x.i + 0x7fffu + ((x.i >> 16) & 1u);
    return (unsigned short)(r >> 16);
}
__device__ __forceinline__ float bf2f(unsigned short u) {
    union { unsigned int i; float f; } x; x.i = ((unsigned int)u) << 16; return x.f;
}
__device__ __forceinline__ float sigm(float x) { return 1.0f / (1.0f + __expf(-x)); }

// swizzled addressing for 256-col bf16 buffers
__device__ __forceinline__ int swz(int row, int col) {
    return row*256 + ((((col >> 3)) ^ (row & 7)) << 3) + (col & 7);
}
__device__ __forceinline__ int swzf(int row, int frag) {   // 8-elem fragment base
    return row*256 + ((frag ^ (row & 7)) << 3);
}
// swizzled addressing for 64-col bf16 msg buffer
__device__ __forceinline__ int swz64(int row, int col) {
    return row*64 + ((((col >> 3)) ^ (row & 7)) << 3) + (col & 7);
}
__device__ __forceinline__ int swzf64(int row, int frag) {
    return row*64 + ((frag ^ (row & 7)) << 3);
}

__device__ __forceinline__ bf16x8 ldfrag(const unsigned short* p) {
    return *(const bf16x8*)(const void*)p;
}
union ZU { uint4 u; bf16x8 v; };
__device__ __forceinline__ bf16x8 zfrag() {
    ZU x; x.u = make_uint4(0u, 0u, 0u, 0u); return x.v;
}
#define MFMA(a,b,c) __builtin_amdgcn_mfma_f32_16x16x32_bf16(a,b,c,0,0,0)

// ---- pre-pass: convert fp32 weight matrices to bf16 in d_ws ----
__global__ void __launch_bounds__(256)
convert_weights(const float* __restrict__ W1,  const float* __restrict__ Wih,
                const float* __restrict__ Whh, const float* __restrict__ Wq,
                const float* __restrict__ Wk,  const float* __restrict__ Wv,
                const float* __restrict__ Wg,  const float* __restrict__ Wp1,
                const float* __restrict__ Wp2, unsigned short* __restrict__ dst)
{
    int b = (int)blockIdx.x;
    const float* src; int base;
    if      (b <  64) { src = W1;  base = WO_W1;              }
    else if (b < 256) { src = Wih; base = WO_WIH; b -=  64;   }
    else if (b < 448) { src = Whh; base = WO_WHH; b -= 256;   }
    else if (b < 464) { src = Wq;  base = WO_WQ;  b -= 448;   }
    else if (b < 480) { src = Wk;  base = WO_WK;  b -= 464;   }
    else if (b < 496) { src = Wv;  base = WO_WV;  b -= 480;   }
    else if (b < 497) { src = Wg;  base = WO_WG;  b -= 496;   }
    else if (b < 577) { src = Wp1; base = WO_WP1; b -= 497;   }
    else              { src = Wp2; base = WO_WP2; b -= 577;   }
    const int idx = b * 1024 + (int)threadIdx.x * 4;
    float4 v = *(const float4*)(const void*)(src + idx);
    ushort4 u;
    u.x = f2bf(v.x); u.y = f2bf(v.y); u.z = f2bf(v.z); u.w = f2bf(v.w);
    *(ushort4*)(void*)(dst + base + idx) = u;
}

__global__ void __launch_bounds__(256, 3)
mappo_fused(const float* __restrict__ gIn,
            const float* __restrict__ gH,
            const unsigned short* __restrict__ wsW,
            const float* __restrict__ B1,
            const float* __restrict__ Bih, const float* __restrict__ Bhh,
            const float* __restrict__ Bq,  const float* __restrict__ Bk,
            const float* __restrict__ Bv,  const float* __restrict__ Bg,
            const float* __restrict__ Bp1, const float* __restrict__ Bp2,
            float* __restrict__ outL, float* __restrict__ outH)
{
    __shared__ __align__(16) char smem[SMEM_TOTAL];

    const unsigned short* W1  = wsW + WO_W1;
    const unsigned short* Wih = wsW + WO_WIH;
    const unsigned short* Whh = wsW + WO_WHH;
    const unsigned short* Wq  = wsW + WO_WQ;
    const unsigned short* Wk  = wsW + WO_WK;
    const unsigned short* Wv  = wsW + WO_WV;
    const unsigned short* Wg  = wsW + WO_WG;
    const unsigned short* Wp1 = wsW + WO_WP1;
    const unsigned short* Wp2 = wsW + WO_WP2;

    const int tid  = (int)threadIdx.x;
    const int lane = tid & 63;
    const int wv   = tid >> 6;
    const int l15  = lane & 15;
    const int quad = lane >> 4;
    const long rowBase = (long)blockIdx.x * NAG;

    // ---- Phase 0: stage fp32 input + h_old into LDS as swizzled bf16 ----
    {
        #pragma unroll
        for (int i = 0; i < 8; ++i) {
            const int job  = i*256 + tid;
            const int frag = job & 31;
            const int row  = (job >> 5) & 31;
            const int buf  = job >> 10;
            const float* src = (buf ? gH : gIn) + (rowBase + row)*256 + frag*8;
            float4 v0 = *(const float4*)(const void*)(src);
            float4 v1 = *(const float4*)(const void*)(src + 4);
            uint4 pk;
            pk.x = ((unsigned int)f2bf(v0.y) << 16) | f2bf(v0.x);
            pk.y = ((unsigned int)f2bf(v0.w) << 16) | f2bf(v0.z);
            pk.z = ((unsigned int)f2bf(v1.y) << 16) | f2bf(v1.x);
            pk.w = ((unsigned int)f2bf(v1.w) << 16) | f2bf(v1.z);
            unsigned short* dst = (unsigned short*)(smem + (buf ? OFF_QK : OFF_X));
            *(uint4*)(void*)(dst + swzf(row, frag)) = pk;
        }
    }
    __syncthreads();

    // ---- Phase 1: x = relu(In @ W1^T + b1) -> regs -> OFF_X (bf16, over IN) ----
    {
        const unsigned short* ldsIN = (const unsigned short*)(smem + OFF_X);
        f32x4 xa[4][2];
        #pragma unroll
        for (int nt4 = 0; nt4 < 4; ++nt4) {
            const int nt = nt4*4 + wv;
            const int n = nt*16 + l15;
            f32x4 acc0 = {0.f,0.f,0.f,0.f}, acc1 = {0.f,0.f,0.f,0.f};
            #pragma unroll
            for (int kt = 0; kt < 8; ++kt) {
                const int frag = kt*4 + quad;
                bf16x8 bf_ = ldfrag(W1 + n*INDIM + frag*8);
                bf16x8 a0  = ldfrag(ldsIN + swzf(l15, frag));
                bf16x8 a1  = ldfrag(ldsIN + swzf(16 + l15, frag));
                acc0 = MFMA(a0, bf_, acc0);
                acc1 = MFMA(a1, bf_, acc1);
            }
            const float bias = B1[n];
            #pragma unroll
            for (int r = 0; r < 4; ++r) {
                acc0[r] = fmaxf(acc0[r] + bias, 0.0f);
                acc1[r] = fmaxf(acc1[r] + bias, 0.0f);
            }
            xa[nt4][0] = acc0; xa[nt4][1] = acc1;
        }
        __syncthreads();   // all IN reads complete
        unsigned short* ldsX = (unsigned short*)(smem + OFF_X);
        #pragma unroll
        for (int nt4 = 0; nt4 < 4; ++nt4) {
            const int nt = nt4*4 + wv;
            #pragma unroll
            for (int r = 0; r < 4; ++r) {
                ldsX[swz(quad*4 + r,      nt*16 + l15)] = f2bf(xa[nt4][0][r]);
                ldsX[swz(16 + quad*4 + r, nt*16 + l15)] = f2bf(xa[nt4][1][r]);
            }
        }
    }
    __syncthreads();

    // ---- Phase 2: GRU -> h_new (OFF_H bf16 + outH fp32) ----
    {
        const unsigned short* ldsX  = (const unsigned short*)(smem + OFF_X);
        const unsigned short* ldsHO = (const unsigned short*)(smem + OFF_QK);
        unsigned short* ldsH        = (unsigned short*)(smem + OFF_H);
        for (int jt = wv; jt < 16; jt += 4) {
            const int n = jt*16 + l15;
            f32x4 gir0={0.f,0.f,0.f,0.f}, gir1={0.f,0.f,0.f,0.f};
            f32x4 giz0={0.f,0.f,0.f,0.f}, giz1={0.f,0.f,0.f,0.f};
            f32x4 gin0={0.f,0.f,0.f,0.f}, gin1={0.f,0.f,0.f,0.f};
            f32x4 ghr0={0.f,0.f,0.f,0.f}, ghr1={0.f,0.f,0.f,0.f};
            f32x4 ghz0={0.f,0.f,0.f,0.f}, ghz1={0.f,0.f,0.f,0.f};
            f32x4 ghn0={0.f,0.f,0.f,0.f}, ghn1={0.f,0.f,0.f,0.f};
            #pragma unroll 2
            for (int kt = 0; kt < 8; ++kt) {
                const int frag = kt*4 + quad;
                const int k0 = frag*8;
                bf16x8 ax0 = ldfrag(ldsX  + swzf(l15, frag));
                bf16x8 ax1 = ldfrag(ldsX  + swzf(16 + l15, frag));
                bf16x8 ah0 = ldfrag(ldsHO + swzf(l15, frag));
                bf16x8 ah1 = ldfrag(ldsHO + swzf(16 + l15, frag));
                bf16x8 bir = ldfrag(Wih + (n      )*HIDD + k0);
                bf16x8 biz = ldfrag(Wih + (n + 256)*HIDD + k0);
                bf16x8 bin = ldfrag(Wih + (n + 512)*HIDD + k0);
                bf16x8 bhr = ldfrag(Whh + (n      )*HIDD + k0);
                bf16x8 bhz = ldfrag(Whh + (n + 256)*HIDD + k0);
                bf16x8 bhn = ldfrag(Whh + (n + 512)*HIDD + k0);
                gir0 = MFMA(ax0, bir, gir0); gir1 = MFMA(ax1, bir, gir1);
                giz0 = MFMA(ax0, biz, giz0); giz1 = MFMA(ax1, biz, giz1);
                gin0 = MFMA(ax0, bin, gin0); gin1 = MFMA(ax1, bin, gin1);
                ghr0 = MFMA(ah0, bhr, ghr0); ghr1 = MFMA(ah1, bhr, ghr1);
                ghz0 = MFMA(ah0, bhz, ghz0); ghz1 = MFMA(ah1, bhz, ghz1);
                ghn0 = MFMA(ah0, bhn, ghn0); ghn1 = MFMA(ah1, bhn, ghn1);
            }
            const float bir_ = Bih[n], biz_ = Bih[n+256], bin_ = Bih[n+512];
            const float bhr_ = Bhh[n], bhz_ = Bhh[n+256], bhn_ = Bhh[n+512];
            #pragma unroll
            for (int mt = 0; mt < 2; ++mt) {
                f32x4 gr = mt ? gir1 : gir0;
                f32x4 gz = mt ? giz1 : giz0;
                f32x4 gn = mt ? gin1 : gin0;
                f32x4 hr = mt ? ghr1 : ghr0;
                f32x4 hz = mt ? ghz1 : ghz0;
                f32x4 hn = mt ? ghn1 : ghn0;
                #pragma unroll
                for (int r = 0; r < 4; ++r) {
                    const int row = mt*16 + quad*4 + r;
                    const int col = jt*16 + l15;
                    float hprev = bf2f(ldsHO[swz(row, col)]);
                    float rr = sigm(gr[r] + bir_ + hr[r] + bhr_);
                    float zz = sigm(gz[r] + biz_ + hz[r] + bhz_);
                    float nn = tanhf(gn[r] + bin_ + rr*(hn[r] + bhn_));
                    float hv = (1.0f - zz)*nn + zz*hprev;
                    ldsH[swz(row, col)] = f2bf(hv);
                    outH[(rowBase + row)*HIDD + col] = hv;
                }
            }
        }
    }
    __syncthreads();

    // ---- Phase 3: q,k (fp32 -> OFF_QK), v,g (bf16 -> OFF_V/OFF_G) ----
    {
        const unsigned short* ldsH = (const unsigned short*)(smem + OFF_H);
        float*          ldsQK = (float*)(smem + OFF_QK);
        unsigned short* ldsV  = (unsigned short*)(smem + OFF_V);
        unsigned short* ldsG  = (unsigned short*)(smem + OFF_G);
        for (int job = wv; job < 13; job += 4) {
            const unsigned short *W;
            const float *Bi;
            int nb;
            if (job < 4)       { W = Wq; Bi = Bq; nb = job*16;      }
            else if (job < 8)  { W = Wk; Bi = Bk; nb = (job-4)*16;  }
            else if (job < 12) { W = Wv; Bi = Bv; nb = (job-8)*16;  }
            else               { W = Wg; Bi = Bg; nb = 0;           }
            const bool valid = (job < 12) || (l15 < 4);
            const int n = nb + l15;
            f32x4 acc0 = {0.f,0.f,0.f,0.f}, acc1 = {0.f,0.f,0.f,0.f};
            #pragma unroll
            for (int kt = 0; kt < 8; ++kt) {
                const int frag = kt*4 + quad;
                bf16x8 bf_ = valid ? ldfrag(W + n*HIDD + frag*8) : zfrag();
                bf16x8 a0  = ldfrag(ldsH + swzf(l15, frag));
                bf16x8 a1  = ldfrag(ldsH + swzf(16 + l15, frag));
                acc0 = MFMA(a0, bf_, acc0);
                acc1 = MFMA(a1, bf_, acc1);
            }
            if (valid) {
                const float bias = Bi[n];
                #pragma unroll
                for (int r = 0; r < 4; ++r) {
                    const int r0 = quad*4 + r, r1 = 16 + quad*4 + r;
                    float v0 = acc0[r] + bias, v1 = acc1[r] + bias;
                    if (job < 4) {
                        ldsQK[r0*QKSTR + job*16 + l15] = v0;
                        ldsQK[r1*QKSTR + job*16 + l15] = v1;
                    } else if (job < 8) {
                        ldsQK[r0*QKSTR + 64 + (job-4)*16 + l15] = v0;
                        ldsQK[r1*QKSTR + 64 + (job-4)*16 + l15] = v1;
                    } else if (job < 12) {
                        ldsV[r0*68 + (job-8)*16 + l15] = f2bf(v0);
                        ldsV[r1*68 + (job-8)*16 + l15] = f2bf(v1);
                    } else {
                        ldsG[r0*4 + l15] = f2bf(v0);
                        ldsG[r1*4 + l15] = f2bf(v1);
                    }
                }
            }
        }
    }
    __syncthreads();

    // ---- Phase 4: sparse attention, 1 thread per (head, query-agent) ----
    {
        const float* ldsQK = (const float*)(smem + OFF_QK);
        const unsigned short* ldsV = (const unsigned short*)(smem + OFF_V);
        const unsigned short* ldsG = (const unsigned short*)(smem + OFF_G);
        float msg[16];
        const int h  = tid >> 5;
        const int qi = tid & 31;
        if (tid < 128) {
            float qv[16];
            #pragma unroll
            for (int c = 0; c < 16; ++c) qv[c] = ldsQK[qi*QKSTR + h*16 + c];
            float s0[32];
            #pragma unroll
            for (int ki = 0; ki < 32; ++ki) {
                float acc = 0.0f;
                #pragma unroll
                for (int c = 0; c < 16; ++c) acc += qv[c] * ldsQK[ki*QKSTR + 64 + h*16 + c];
                acc *= 0.25f;                       // 1/sqrt(16)
                s0[ki] = (ki == qi) ? NEGV : acc;   // diagonal mask
            }
            // top-8, lowest index wins ties (matches lax.top_k)
            unsigned int mask = 0u;
            float m1 = 0.0f;
            for (int t = 0; t < 8; ++t) {
                float best = -3.0e38f; int bidx = 0;
                #pragma unroll
                for (int i = 0; i < 32; ++i) {
                    bool better = (((mask >> i) & 1u) == 0u) && (s0[i] > best);
                    best = better ? s0[i] : best;
                    bidx = better ? i : bidx;
                }
                mask |= (1u << bidx);
                if (t == 0) m1 = best;
            }
            float sum = 0.0f;
            #pragma unroll
            for (int i = 0; i < 32; ++i) {
                float v = ((mask >> i) & 1u) ? s0[i] : NEGV;
                sum += __expf(v - m1);
            }
            const float inv = 1.0f / sum;
            const float gate = sigm(bf2f(ldsG[qi*4 + h]));
            #pragma unroll
            for (int c = 0; c < 16; ++c) msg[c] = 0.0f;
            #pragma unroll
            for (int ki = 0; ki < 32; ++ki) {
                float v = ((mask >> ki) & 1u) ? s0[ki] : NEGV;
                float al = __expf(v - m1) * inv;
                #pragma unroll
                for (int c = 0; c < 16; ++c) msg[c] += al * bf2f(ldsV[ki*68 + h*16 + c]);
            }
            #pragma unroll
            for (int c = 0; c < 16; ++c) msg[c] *= gate;
        }
        __syncthreads();   // all v/g reads complete
        if (tid < 128) {
            unsigned short* ldsM = (unsigned short*)(smem + OFF_V);  // overlay
            #pragma unroll
            for (int c = 0; c < 16; ++c) ldsM[swz64(qi, h*16 + c)] = f2bf(msg[c]);
        }
    }
    __syncthreads();

    // ---- Phase 5: p1x = relu([h | msg] @ Wp1^T + b) -> OFF_X (bf16) ----
    {
        const unsigned short* ldsH = (const unsigned short*)(smem + OFF_H);
        const unsigned short* ldsM = (const unsigned short*)(smem + OFF_V);
        unsigned short* ldsP = (unsigned short*)(smem + OFF_X);
        for (int nt = wv; nt < 16; nt += 4) {
            const int n = nt*16 + l15;
            f32x4 acc0 = {0.f,0.f,0.f,0.f}, acc1 = {0.f,0.f,0.f,0.f};
            #pragma unroll
            for (int kt = 0; kt < 10; ++kt) {
                bf16x8 bf_ = ldfrag(Wp1 + n*PIN + kt*32 + quad*8);
                bf16x8 a0, a1;
                if (kt < 8) {
                    const int frag = kt*4 + quad;
                    a0 = ldfrag(ldsH + swzf(l15, frag));
                    a1 = ldfrag(ldsH + swzf(16 + l15, frag));
                } else {
                    const int frag = (kt-8)*4 + quad;
                    a0 = ldfrag(ldsM + swzf64(l15, frag));
                    a1 = ldfrag(ldsM + swzf64(16 + l15, frag));
                }
                acc0 = MFMA(a0, bf_, acc0);
                acc1 = MFMA(a1, bf_, acc1);
            }
            const float bias = Bp1[n];
            #pragma unroll
            for (int r = 0; r < 4; ++r) {
                ldsP[swz(quad*4 + r,      nt*16 + l15)] = f2bf(fmaxf(acc0[r] + bias, 0.0f));
                ldsP[swz(16 + quad*4 + r, nt*16 + l15)] = f2bf(fmaxf(acc1[r] + bias, 0.0f));
            }
        }
    }
    __syncthreads();

    // ---- Phase 6: logits = p1x @ Wp2^T + b -> outL (fp32) ----
    {
        const unsigned short* ldsP = (const unsigned short*)(smem + OFF_X);
        const int nt = wv >> 1;
        const int mt = wv & 1;
        const int n = nt*16 + l15;
        const bool valid = (n < NACTN);
        f32x4 acc = {0.f,0.f,0.f,0.f};
        #pragma unroll
        for (int kt = 0; kt < 8; ++kt) {
            const int frag = kt*4 + quad;
            bf16x8 bf_ = valid ? ldfrag(Wp2 + n*HIDD + frag*8) : zfrag();
            bf16x8 a   = ldfrag(ldsP + swzf(mt*16 + l15, frag));
            acc = MFMA(a, bf_, acc);
        }
        if (valid) {
            const float bias = Bp2[n];
            #pragma unroll
            for (int r = 0; r < 4; ++r) {
                const int row = mt*16 + quad*4 + r;
                outL[(rowBase + row)*NACTN + n] = acc[r] + bias;
            }
        }
    }
}

extern "C" void kernel_launch(void* const* d_in, const int* in_sizes, int n_in,
                              void* d_out, int out_size, void* d_ws, size_t ws_size,
                              hipStream_t stream) {
    (void)in_sizes; (void)n_in; (void)ws_size; (void)out_size;
    const float* gIn = (const float*)d_in[0];
    const float* gH  = (const float*)d_in[1];
    const float* W1  = (const float*)d_in[2];
    const float* B1  = (const float*)d_in[3];
    const float* Wih = (const float*)d_in[4];
    const float* Whh = (const float*)d_in[5];
    const float* Bih = (const float*)d_in[6];
    const float* Bhh = (const float*)d_in[7];
    const float* Wq  = (const float*)d_in[8];
    const float* Bq  = (const float*)d_in[9];
    const float* Wk  = (const float*)d_in[10];
    const float* Bk  = (const float*)d_in[11];
    const float* Wv  = (const float*)d_in[12];
    const float* Bv  = (const float*)d_in[13];
    const float* Wg  = (const float*)d_in[14];
    const float* Bg  = (const float*)d_in[15];
    const float* Wp1 = (const float*)d_in[16];
    const float* Bp1 = (const float*)d_in[17];
    const float* Wp2 = (const float*)d_in[18];
    const float* Bp2 = (const float*)d_in[19];
    float* outL = (float*)d_out;
    float* outH = outL + (size_t)NBATCH * NAG * NACTN;
    unsigned short* wsW = (unsigned short*)d_ws;

    hipLaunchKernelGGL(convert_weights, dim3(582), dim3(256), 0, stream,
        W1, Wih, Whh, Wq, Wk, Wv, Wg, Wp1, Wp2, wsW);
    hipLaunchKernelGGL(mappo_fused, dim3(NBATCH), dim3(256), 0, stream,
        gIn, gH, wsW, B1, Bih, Bhh, Bq, Bk, Bv, Bg, Bp1, Bp2, outL, outH);
}

// Round 6
// 531.319 us; speedup vs baseline: 1.0754x; 1.0754x over previous
//
#include <hip/hip_runtime.h>
#include <hip/hip_bf16.h>
#include <math.h>

#define NBATCH 2048
#define NAG 32
#define HIDD 256
#define INDIM 256
#define PIN 320
#define NACTN 20
#define NEGV -1e10f

typedef __attribute__((ext_vector_type(8))) __bf16 bf16x8;
typedef __attribute__((ext_vector_type(4))) float f32x4;

// LDS regions (byte offsets). bf16 activation buffers are 32x256,
// XOR-swizzled (frag ^= row&7), stride 256 elems, no padding.
// Total 49,152 B = 24 x 2KiB = 12 x 4KiB (granule-proof) -> 3 blocks/CU.
#define OFF_X   0         // bf16: input -> x -> p1x (overlaid live ranges)
#define OFF_HO  16384     // bf16 h_old (32x256 swz) -> qk bf16 (32x132) + v + g
#define OFF_QK  16384     //   qk: q cols 0-63, k cols 64-127, stride 132, 8448 B
#define OFF_V   24832     //   v: 32x68 bf16 (4352 B); msg overlays (32x64 swz)
#define OFF_G   29184     //   g: 32x4 bf16 (256 B)
#define OFF_H   32768     // bf16 h_new (32x256 swz)
#define SMEM_TOTAL 49152
#define QKSTR 132         // bf16 q|k row stride

// bf16 weight cache layout in d_ws (element offsets)
#define WO_W1   0
#define WO_WIH  65536
#define WO_WHH  262144
#define WO_WQ   458752
#define WO_WK   475136
#define WO_WV   491520
#define WO_WG   507904
#define WO_WP1  508928
#define WO_WP2  590848

__device__ __forceinline__ unsigned short f2bf(float f) {
    union { float f; unsigned int i; } x; x.f = f;
    unsigned int r = x.i + 0x7fffu + ((x.i >> 16) & 1u);
    return (unsigned short)(r >> 16);
}
__device__ __forceinline__ float bf2f(unsigned short u) {
    union { unsigned int i; float f; } x; x.i = ((unsigned int)u) << 16; return x.f;
}
__device__ __forceinline__ float sigm(float x) { return 1.0f / (1.0f + __expf(-x)); }

// swizzled addressing for 256-col bf16 buffers
__device__ __forceinline__ int swz(int row, int col) {
    return row*256 + ((((col >> 3)) ^ (row & 7)) << 3) + (col & 7);
}
__device__ __forceinline__ int swzf(int row, int frag) {   // 8-elem fragment base
    return row*256 + ((frag ^ (row & 7)) << 3);
}
// swizzled addressing for 64-col bf16 msg buffer
__device__ __forceinline__ int swz64(int row, int col) {
    return row*64 + ((((col >> 3)) ^ (row & 7)) << 3) + (col & 7);
}
__device__ __forceinline__ int swzf64(int row, int frag) {
    return row*64 + ((frag ^ (row & 7)) << 3);
}

__device__ __forceinline__ bf16x8 ldfrag(const unsigned short* p) {
    return *(const bf16x8*)(const void*)p;
}
union ZU { uint4 u; bf16x8 v; };
__device__ __forceinline__ bf16x8 zfrag() {
    ZU x; x.u = make_uint4(0u, 0u, 0u, 0u); return x.v;
}
#define MFMA(a,b,c) __builtin_amdgcn_mfma_f32_16x16x32_bf16(a,b,c,0,0,0)

// ---- pre-pass: convert fp32 weight matrices to bf16 in d_ws ----
__global__ void __launch_bounds__(256)
convert_weights(const float* __restrict__ W1,  const float* __restrict__ Wih,
                const float* __restrict__ Whh, const float* __restrict__ Wq,
                const float* __restrict__ Wk,  const float* __restrict__ Wv,
                const float* __restrict__ Wg,  const float* __restrict__ Wp1,
                const float* __restrict__ Wp2, unsigned short* __restrict__ dst)
{
    int b = (int)blockIdx.x;
    const float* src; int base;
    if      (b <  64) { src = W1;  base = WO_W1;              }
    else if (b < 256) { src = Wih; base = WO_WIH; b -=  64;   }
    else if (b < 448) { src = Whh; base = WO_WHH; b -= 256;   }
    else if (b < 464) { src = Wq;  base = WO_WQ;  b -= 448;   }
    else if (b < 480) { src = Wk;  base = WO_WK;  b -= 464;   }
    else if (b < 496) { src = Wv;  base = WO_WV;  b -= 480;   }
    else if (b < 497) { src = Wg;  base = WO_WG;  b -= 496;   }
    else if (b < 577) { src = Wp1; base = WO_WP1; b -= 497;   }
    else              { src = Wp2; base = WO_WP2; b -= 577;   }
    const int idx = b * 1024 + (int)threadIdx.x * 4;
    float4 v = *(const float4*)(const void*)(src + idx);
    ushort4 u;
    u.x = f2bf(v.x); u.y = f2bf(v.y); u.z = f2bf(v.z); u.w = f2bf(v.w);
    *(ushort4*)(void*)(dst + base + idx) = u;
}

__global__ void __launch_bounds__(256, 3)
mappo_fused(const float* __restrict__ gIn,
            const float* __restrict__ gH,
            const unsigned short* __restrict__ wsW,
            const float* __restrict__ B1,
            const float* __restrict__ Bih, const float* __restrict__ Bhh,
            const float* __restrict__ Bq,  const float* __restrict__ Bk,
            const float* __restrict__ Bv,  const float* __restrict__ Bg,
            const float* __restrict__ Bp1, const float* __restrict__ Bp2,
            float* __restrict__ outL, float* __restrict__ outH)
{
    __shared__ __align__(16) char smem[SMEM_TOTAL];

    const unsigned short* W1  = wsW + WO_W1;
    const unsigned short* Wih = wsW + WO_WIH;
    const unsigned short* Whh = wsW + WO_WHH;
    const unsigned short* Wq  = wsW + WO_WQ;
    const unsigned short* Wk  = wsW + WO_WK;
    const unsigned short* Wv  = wsW + WO_WV;
    const unsigned short* Wg  = wsW + WO_WG;
    const unsigned short* Wp1 = wsW + WO_WP1;
    const unsigned short* Wp2 = wsW + WO_WP2;

    const int tid  = (int)threadIdx.x;
    const int lane = tid & 63;
    const int wv   = tid >> 6;
    const int l15  = lane & 15;
    const int quad = lane >> 4;
    const long rowBase = (long)blockIdx.x * NAG;

    // ---- Phase 0: stage fp32 input + h_old into LDS as swizzled bf16 ----
    {
        #pragma unroll
        for (int i = 0; i < 8; ++i) {
            const int job  = i*256 + tid;
            const int frag = job & 31;
            const int row  = (job >> 5) & 31;
            const int buf  = job >> 10;
            const float* src = (buf ? gH : gIn) + (rowBase + row)*256 + frag*8;
            float4 v0 = *(const float4*)(const void*)(src);
            float4 v1 = *(const float4*)(const void*)(src + 4);
            uint4 pk;
            pk.x = ((unsigned int)f2bf(v0.y) << 16) | f2bf(v0.x);
            pk.y = ((unsigned int)f2bf(v0.w) << 16) | f2bf(v0.z);
            pk.z = ((unsigned int)f2bf(v1.y) << 16) | f2bf(v1.x);
            pk.w = ((unsigned int)f2bf(v1.w) << 16) | f2bf(v1.z);
            unsigned short* dst = (unsigned short*)(smem + (buf ? OFF_HO : OFF_X));
            *(uint4*)(void*)(dst + swzf(row, frag)) = pk;
        }
    }
    __syncthreads();

    // ---- Phase 1: x = relu(In @ W1^T + b1) -> regs -> OFF_X (bf16, over IN) ----
    {
        const unsigned short* ldsIN = (const unsigned short*)(smem + OFF_X);
        f32x4 xa[4][2];
        #pragma unroll
        for (int nt4 = 0; nt4 < 4; ++nt4) {
            const int nt = nt4*4 + wv;
            const int n = nt*16 + l15;
            f32x4 acc0 = {0.f,0.f,0.f,0.f}, acc1 = {0.f,0.f,0.f,0.f};
            #pragma unroll
            for (int kt = 0; kt < 8; ++kt) {
                const int frag = kt*4 + quad;
                bf16x8 bf_ = ldfrag(W1 + n*INDIM + frag*8);
                bf16x8 a0  = ldfrag(ldsIN + swzf(l15, frag));
                bf16x8 a1  = ldfrag(ldsIN + swzf(16 + l15, frag));
                acc0 = MFMA(a0, bf_, acc0);
                acc1 = MFMA(a1, bf_, acc1);
            }
            const float bias = B1[n];
            #pragma unroll
            for (int r = 0; r < 4; ++r) {
                acc0[r] = fmaxf(acc0[r] + bias, 0.0f);
                acc1[r] = fmaxf(acc1[r] + bias, 0.0f);
            }
            xa[nt4][0] = acc0; xa[nt4][1] = acc1;
        }
        __syncthreads();   // all IN reads complete
        unsigned short* ldsX = (unsigned short*)(smem + OFF_X);
        #pragma unroll
        for (int nt4 = 0; nt4 < 4; ++nt4) {
            const int nt = nt4*4 + wv;
            #pragma unroll
            for (int r = 0; r < 4; ++r) {
                ldsX[swz(quad*4 + r,      nt*16 + l15)] = f2bf(xa[nt4][0][r]);
                ldsX[swz(16 + quad*4 + r, nt*16 + l15)] = f2bf(xa[nt4][1][r]);
            }
        }
    }
    __syncthreads();

    // ---- Phase 2: GRU -> h_new (OFF_H bf16 + outH fp32) ----
    {
        const unsigned short* ldsX  = (const unsigned short*)(smem + OFF_X);
        const unsigned short* ldsHO = (const unsigned short*)(smem + OFF_HO);
        unsigned short* ldsH        = (unsigned short*)(smem + OFF_H);
        for (int jt = wv; jt < 16; jt += 4) {
            const int n = jt*16 + l15;
            f32x4 gir0={0.f,0.f,0.f,0.f}, gir1={0.f,0.f,0.f,0.f};
            f32x4 giz0={0.f,0.f,0.f,0.f}, giz1={0.f,0.f,0.f,0.f};
            f32x4 gin0={0.f,0.f,0.f,0.f}, gin1={0.f,0.f,0.f,0.f};
            f32x4 ghr0={0.f,0.f,0.f,0.f}, ghr1={0.f,0.f,0.f,0.f};
            f32x4 ghz0={0.f,0.f,0.f,0.f}, ghz1={0.f,0.f,0.f,0.f};
            f32x4 ghn0={0.f,0.f,0.f,0.f}, ghn1={0.f,0.f,0.f,0.f};
            #pragma unroll 2
            for (int kt = 0; kt < 8; ++kt) {
                const int frag = kt*4 + quad;
                const int k0 = frag*8;
                bf16x8 ax0 = ldfrag(ldsX  + swzf(l15, frag));
                bf16x8 ax1 = ldfrag(ldsX  + swzf(16 + l15, frag));
                bf16x8 ah0 = ldfrag(ldsHO + swzf(l15, frag));
                bf16x8 ah1 = ldfrag(ldsHO + swzf(16 + l15, frag));
                bf16x8 bir = ldfrag(Wih + (n      )*HIDD + k0);
                bf16x8 biz = ldfrag(Wih + (n + 256)*HIDD + k0);
                bf16x8 bin = ldfrag(Wih + (n + 512)*HIDD + k0);
                bf16x8 bhr = ldfrag(Whh + (n      )*HIDD + k0);
                bf16x8 bhz = ldfrag(Whh + (n + 256)*HIDD + k0);
                bf16x8 bhn = ldfrag(Whh + (n + 512)*HIDD + k0);
                gir0 = MFMA(ax0, bir, gir0); gir1 = MFMA(ax1, bir, gir1);
                giz0 = MFMA(ax0, biz, giz0); giz1 = MFMA(ax1, biz, giz1);
                gin0 = MFMA(ax0, bin, gin0); gin1 = MFMA(ax1, bin, gin1);
                ghr0 = MFMA(ah0, bhr, ghr0); ghr1 = MFMA(ah1, bhr, ghr1);
                ghz0 = MFMA(ah0, bhz, ghz0); ghz1 = MFMA(ah1, bhz, ghz1);
                ghn0 = MFMA(ah0, bhn, ghn0); ghn1 = MFMA(ah1, bhn, ghn1);
            }
            const float bir_ = Bih[n], biz_ = Bih[n+256], bin_ = Bih[n+512];
            const float bhr_ = Bhh[n], bhz_ = Bhh[n+256], bhn_ = Bhh[n+512];
            #pragma unroll
            for (int mt = 0; mt < 2; ++mt) {
                f32x4 gr = mt ? gir1 : gir0;
                f32x4 gz = mt ? giz1 : giz0;
                f32x4 gn = mt ? gin1 : gin0;
                f32x4 hr = mt ? ghr1 : ghr0;
                f32x4 hz = mt ? ghz1 : ghz0;
                f32x4 hn = mt ? ghn1 : ghn0;
                #pragma unroll
                for (int r = 0; r < 4; ++r) {
                    const int row = mt*16 + quad*4 + r;
                    const int col = jt*16 + l15;
                    float hprev = bf2f(ldsHO[swz(row, col)]);
                    float rr = sigm(gr[r] + bir_ + hr[r] + bhr_);
                    float zz = sigm(gz[r] + biz_ + hz[r] + bhz_);
                    float nn = tanhf(gn[r] + bin_ + rr*(hn[r] + bhn_));
                    float hv = (1.0f - zz)*nn + zz*hprev;
                    ldsH[swz(row, col)] = f2bf(hv);
                    outH[(rowBase + row)*HIDD + col] = hv;
                }
            }
        }
    }
    __syncthreads();

    // ---- Phase 3: q,k (bf16 -> OFF_QK over h_old), v,g (bf16 -> OFF_V/OFF_G) ----
    {
        const unsigned short* ldsH = (const unsigned short*)(smem + OFF_H);
        unsigned short* ldsQK = (unsigned short*)(smem + OFF_QK);
        unsigned short* ldsV  = (unsigned short*)(smem + OFF_V);
        unsigned short* ldsG  = (unsigned short*)(smem + OFF_G);
        for (int job = wv; job < 13; job += 4) {
            const unsigned short *W;
            const float *Bi;
            int nb;
            if (job < 4)       { W = Wq; Bi = Bq; nb = job*16;      }
            else if (job < 8)  { W = Wk; Bi = Bk; nb = (job-4)*16;  }
            else if (job < 12) { W = Wv; Bi = Bv; nb = (job-8)*16;  }
            else               { W = Wg; Bi = Bg; nb = 0;           }
            const bool valid = (job < 12) || (l15 < 4);
            const int n = nb + l15;
            f32x4 acc0 = {0.f,0.f,0.f,0.f}, acc1 = {0.f,0.f,0.f,0.f};
            #pragma unroll
            for (int kt = 0; kt < 8; ++kt) {
                const int frag = kt*4 + quad;
                bf16x8 bf_ = valid ? ldfrag(W + n*HIDD + frag*8) : zfrag();
                bf16x8 a0  = ldfrag(ldsH + swzf(l15, frag));
                bf16x8 a1  = ldfrag(ldsH + swzf(16 + l15, frag));
                acc0 = MFMA(a0, bf_, acc0);
                acc1 = MFMA(a1, bf_, acc1);
            }
            if (valid) {
                const float bias = Bi[n];
                #pragma unroll
                for (int r = 0; r < 4; ++r) {
                    const int r0 = quad*4 + r, r1 = 16 + quad*4 + r;
                    float v0 = acc0[r] + bias, v1 = acc1[r] + bias;
                    if (job < 8) {
                        // q cols 0-63, k cols 64-127: col = job*16 + l15
                        ldsQK[r0*QKSTR + job*16 + l15] = f2bf(v0);
                        ldsQK[r1*QKSTR + job*16 + l15] = f2bf(v1);
                    } else if (job < 12) {
                        ldsV[r0*68 + (job-8)*16 + l15] = f2bf(v0);
                        ldsV[r1*68 + (job-8)*16 + l15] = f2bf(v1);
                    } else {
                        ldsG[r0*4 + l15] = f2bf(v0);
                        ldsG[r1*4 + l15] = f2bf(v1);
                    }
                }
            }
        }
    }
    __syncthreads();

    // ---- Phase 4: sparse attention, 1 thread per (head, query-agent) ----
    {
        const unsigned short* ldsQK = (const unsigned short*)(smem + OFF_QK);
        const unsigned short* ldsV  = (const unsigned short*)(smem + OFF_V);
        const unsigned short* ldsG  = (const unsigned short*)(smem + OFF_G);
        float msg[16];
        const int h  = tid >> 5;
        const int qi = tid & 31;
        if (tid < 128) {
            float qv[16];
            #pragma unroll
            for (int c = 0; c < 16; ++c) qv[c] = bf2f(ldsQK[qi*QKSTR + h*16 + c]);
            float s0[32];
            #pragma unroll
            for (int ki = 0; ki < 32; ++ki) {
                float acc = 0.0f;
                #pragma unroll
                for (int c = 0; c < 16; ++c)
                    acc += qv[c] * bf2f(ldsQK[ki*QKSTR + 64 + h*16 + c]);
                acc *= 0.25f;                       // 1/sqrt(16)
                s0[ki] = (ki == qi) ? NEGV : acc;   // diagonal mask
            }
            // top-8, lowest index wins ties (matches lax.top_k)
            unsigned int mask = 0u;
            float m1 = 0.0f;
            for (int t = 0; t < 8; ++t) {
                float best = -3.0e38f; int bidx = 0;
                #pragma unroll
                for (int i = 0; i < 32; ++i) {
                    bool better = (((mask >> i) & 1u) == 0u) && (s0[i] > best);
                    best = better ? s0[i] : best;
                    bidx = better ? i : bidx;
                }
                mask |= (1u << bidx);
                if (t == 0) m1 = best;
            }
            float sum = 0.0f;
            #pragma unroll
            for (int i = 0; i < 32; ++i) {
                float v = ((mask >> i) & 1u) ? s0[i] : NEGV;
                sum += __expf(v - m1);
            }
            const float inv = 1.0f / sum;
            const float gate = sigm(bf2f(ldsG[qi*4 + h]));
            #pragma unroll
            for (int c = 0; c < 16; ++c) msg[c] = 0.0f;
            #pragma unroll
            for (int ki = 0; ki < 32; ++ki) {
                float v = ((mask >> ki) & 1u) ? s0[ki] : NEGV;
                float al = __expf(v - m1) * inv;
                #pragma unroll
                for (int c = 0; c < 16; ++c) msg[c] += al * bf2f(ldsV[ki*68 + h*16 + c]);
            }
            #pragma unroll
            for (int c = 0; c < 16; ++c) msg[c] *= gate;
        }
        __syncthreads();   // all v/g reads complete
        if (tid < 128) {
            unsigned short* ldsM = (unsigned short*)(smem + OFF_V);  // overlay
            #pragma unroll
            for (int c = 0; c < 16; ++c) ldsM[swz64(qi, h*16 + c)] = f2bf(msg[c]);
        }
    }
    __syncthreads();

    // ---- Phase 5: p1x = relu([h | msg] @ Wp1^T + b) -> OFF_X (bf16) ----
    {
        const unsigned short* ldsH = (const unsigned short*)(smem + OFF_H);
        const unsigned short* ldsM = (const unsigned short*)(smem + OFF_V);
        unsigned short* ldsP = (unsigned short*)(smem + OFF_X);
        for (int nt = wv; nt < 16; nt += 4) {
            const int n = nt*16 + l15;
            f32x4 acc0 = {0.f,0.f,0.f,0.f}, acc1 = {0.f,0.f,0.f,0.f};
            #pragma unroll
            for (int kt = 0; kt < 10; ++kt) {
                bf16x8 bf_ = ldfrag(Wp1 + n*PIN + kt*32 + quad*8);
                bf16x8 a0, a1;
                if (kt < 8) {
                    const int frag = kt*4 + quad;
                    a0 = ldfrag(ldsH + swzf(l15, frag));
                    a1 = ldfrag(ldsH + swzf(16 + l15, frag));
                } else {
                    const int frag = (kt-8)*4 + quad;
                    a0 = ldfrag(ldsM + swzf64(l15, frag));
                    a1 = ldfrag(ldsM + swzf64(16 + l15, frag));
                }
                acc0 = MFMA(a0, bf_, acc0);
                acc1 = MFMA(a1, bf_, acc1);
            }
            const float bias = Bp1[n];
            #pragma unroll
            for (int r = 0; r < 4; ++r) {
                ldsP[swz(quad*4 + r,      nt*16 + l15)] = f2bf(fmaxf(acc0[r] + bias, 0.0f));
                ldsP[swz(16 + quad*4 + r, nt*16 + l15)] = f2bf(fmaxf(acc1[r] + bias, 0.0f));
            }
        }
    }
    __syncthreads();

    // ---- Phase 6: logits = p1x @ Wp2^T + b -> outL (fp32) ----
    {
        const unsigned short* ldsP = (const unsigned short*)(smem + OFF_X);
        const int nt = wv >> 1;
        const int mt = wv & 1;
        const int n = nt*16 + l15;
        const bool valid = (n < NACTN);
        f32x4 acc = {0.f,0.f,0.f,0.f};
        #pragma unroll
        for (int kt = 0; kt < 8; ++kt) {
            const int frag = kt*4 + quad;
            bf16x8 bf_ = valid ? ldfrag(Wp2 + n*HIDD + frag*8) : zfrag();
            bf16x8 a   = ldfrag(ldsP + swzf(mt*16 + l15, frag));
            acc = MFMA(a, bf_, acc);
        }
        if (valid) {
            const float bias = Bp2[n];
            #pragma unroll
            for (int r = 0; r < 4; ++r) {
                const int row = mt*16 + quad*4 + r;
                outL[(rowBase + row)*NACTN + n] = acc[r] + bias;
            }
        }
    }
}

extern "C" void kernel_launch(void* const* d_in, const int* in_sizes, int n_in,
                              void* d_out, int out_size, void* d_ws, size_t ws_size,
                              hipStream_t stream) {
    (void)in_sizes; (void)n_in; (void)ws_size; (void)out_size;
    const float* gIn = (const float*)d_in[0];
    const float* gH  = (const float*)d_in[1];
    const float* W1  = (const float*)d_in[2];
    const float* B1  = (const float*)d_in[3];
    const float* Wih = (const float*)d_in[4];
    const float* Whh = (const float*)d_in[5];
    const float* Bih = (const float*)d_in[6];
    const float* Bhh = (const float*)d_in[7];
    const float* Wq  = (const float*)d_in[8];
    const float* Bq  = (const float*)d_in[9];
    const float* Wk  = (const float*)d_in[10];
    const float* Bk  = (const float*)d_in[11];
    const float* Wv  = (const float*)d_in[12];
    const float* Bv  = (const float*)d_in[13];
    const float* Wg  = (const float*)d_in[14];
    const float* Bg  = (const float*)d_in[15];
    const float* Wp1 = (const float*)d_in[16];
    const float* Bp1 = (const float*)d_in[17];
    const float* Wp2 = (const float*)d_in[18];
    const float* Bp2 = (const float*)d_in[19];
    float* outL = (float*)d_out;
    float* outH = outL + (size_t)NBATCH * NAG * NACTN;
    unsigned short* wsW = (unsigned short*)d_ws;

    hipLaunchKernelGGL(convert_weights, dim3(582), dim3(256), 0, stream,
        W1, Wih, Whh, Wq, Wk, Wv, Wg, Wp1, Wp2, wsW);
    hipLaunchKernelGGL(mappo_fused, dim3(NBATCH), dim3(256), 0, stream,
        gIn, gH, wsW, B1, Bih, Bhh, Bq, Bk, Bv, Bg, Bp1, Bp2, outL, outH);
}